// Round 1
// baseline (12381.635 us; speedup 1.0000x reference)
//
#include <hip/hip_runtime.h>
#include <math.h>

#define TPB 256

__device__ __forceinline__ float gelu_f(float x) {
  return 0.5f * x * (1.0f + erff(x * 0.70710678118654752f));
}

// ---------------- head conv 3x3, reflect pad, 3->64, writes R and Y ----------------
__global__ void head_conv_kernel(const float* __restrict__ x, const float* __restrict__ w,
                                 const float* __restrict__ bias, float* __restrict__ R,
                                 float* __restrict__ Y) {
  int idx = blockIdx.x * TPB + threadIdx.x;           // 4*64*192*192
  int wc = idx % 192; int t = idx / 192; int h = t % 192; t /= 192; int oc = t % 64; int b = t / 64;
  float acc = bias[oc];
  #pragma unroll
  for (int kh = 0; kh < 3; kh++) {
    int hh = h + kh - 1; hh = (hh < 0) ? -hh : (hh > 191 ? 382 - hh : hh);
    #pragma unroll
    for (int kw = 0; kw < 3; kw++) {
      int ww = wc + kw - 1; ww = (ww < 0) ? -ww : (ww > 191 ? 382 - ww : ww);
      #pragma unroll
      for (int ic = 0; ic < 3; ic++)
        acc += x[((b * 3 + ic) * 192 + hh) * 192 + ww] * w[((oc * 3 + ic) * 3 + kh) * 3 + kw];
    }
  }
  R[idx] = acc; Y[idx] = acc;
}

// ---------------- instance norm: one block per (b,c) ----------------
__global__ void instnorm_kernel(const float* __restrict__ Y, float* __restrict__ Z) {
  int bc = blockIdx.x;
  const float* in = Y + (size_t)bc * 36864;
  float* out = Z + (size_t)bc * 36864;
  double s = 0.0, s2 = 0.0;
  for (int i = threadIdx.x; i < 36864; i += TPB) { float v = in[i]; s += v; s2 += (double)v * v; }
  __shared__ double sh0[TPB]; __shared__ double sh1[TPB];
  sh0[threadIdx.x] = s; sh1[threadIdx.x] = s2; __syncthreads();
  for (int off = 128; off > 0; off >>= 1) {
    if (threadIdx.x < off) { sh0[threadIdx.x] += sh0[threadIdx.x + off]; sh1[threadIdx.x] += sh1[threadIdx.x + off]; }
    __syncthreads();
  }
  __shared__ float mb, rb;
  if (threadIdx.x == 0) {
    double m = sh0[0] / 36864.0;
    double var = sh1[0] / 36864.0 - m * m;
    mb = (float)m; rb = (float)(1.0 / sqrt(var + 1e-5));
  }
  __syncthreads();
  float m = mb, r = rb;
  for (int i = threadIdx.x; i < 36864; i += TPB) out[i] = (in[i] - m) * r;
}

// ---------------- x_g = (x_g + x_{g-1})/2 on 16-ch groups of Z ----------------
__global__ void mix_kernel(float* __restrict__ Z, int g) {
  int idx = blockIdx.x * TPB + threadIdx.x;           // < 4*16*36864
  int b = idx / 589824; int r = idx % 589824;
  size_t cur = (size_t)b * 2359296 + (size_t)g * 589824 + r;
  Z[cur] = 0.5f * (Z[cur] + Z[cur - 589824]);
}

// ---------------- DWT: (B,C,H,W) -> (B,4C,H/2,W/2) [ll,hl,lh,hh] ----------------
__global__ void dwt_kernel(const float* __restrict__ in, float* __restrict__ out,
                           int C, int H, int W, long long ibStride, int ig0) {
  int idx = blockIdx.x * TPB + threadIdx.x;
  int H2 = H >> 1, W2 = W >> 1;
  int w2 = idx % W2; int t = idx / W2; int h2 = t % H2; t /= H2; int c = t % C; int b = t / C;
  const float* ip = in + (size_t)b * ibStride + (size_t)(ig0 + c) * H * W;
  int r0 = 2 * h2 * W + 2 * w2;
  float a = ip[r0], cc = ip[r0 + 1], bb = ip[r0 + W], dd = ip[r0 + W + 1];
  int HW2 = H2 * W2;
  size_t ob = ((size_t)b * 4 * C + c) * HW2 + (size_t)h2 * W2 + w2;
  out[ob] = 0.5f * (a + bb + cc + dd);
  out[ob + (size_t)C * HW2] = 0.5f * (-a - bb + cc + dd);
  out[ob + (size_t)2 * C * HW2] = 0.5f * (-a + bb - cc + dd);
  out[ob + (size_t)3 * C * HW2] = 0.5f * (a - bb - cc + dd);
}

// ---------------- IWT: (B,4C,H,W) -> (B,C,2H,2W), optional add-into strided dest ----------------
__global__ void iwt_kernel(const float* __restrict__ in, float* __restrict__ out,
                           int C, int H, int W, long long obStride, int og0, int addFlag) {
  int idx = blockIdx.x * TPB + threadIdx.x;
  int w = idx % W; int t = idx / W; int h = t % H; t /= H; int c = t % C; int b = t / C;
  size_t HW = (size_t)H * W; size_t CHW = (size_t)C * HW;
  size_t base = (size_t)b * 4 * CHW + (size_t)c * HW + (size_t)h * W + w;
  float x1 = in[base], x2 = in[base + CHW], x3 = in[base + 2 * CHW], x4 = in[base + 3 * CHW];
  float p00 = 0.5f * (x1 - x2 - x3 + x4);
  float p10 = 0.5f * (x1 - x2 + x3 - x4);
  float p01 = 0.5f * (x1 + x2 - x3 - x4);
  float p11 = 0.5f * (x1 + x2 + x3 + x4);
  int W2 = 2 * W;
  float* op = out + (size_t)b * obStride + (size_t)(og0 + c) * (4 * HW) + (size_t)(2 * h) * W2 + 2 * w;
  if (addFlag) { op[0] += p00; op[1] += p01; op[W2] += p10; op[W2 + 1] += p11; }
  else         { op[0] = p00;  op[1] = p01;  op[W2] = p10;  op[W2 + 1] = p11; }
}

// ---------------- qkv einsum: out[b,o,p] = sum_c w[o,c] * in[b,c,p] ----------------
__global__ void qkv_kernel(const float* __restrict__ in, const float* __restrict__ w,
                           float* __restrict__ out, int C, int HW, long long ibStride, int ig0) {
  int idx = blockIdx.x * TPB + threadIdx.x;
  int p = idx % HW; int t = idx / HW; int o = t % (3 * C); int b = t / (3 * C);
  const float* ip = in + (size_t)b * ibStride + (size_t)ig0 * HW + p;
  const float* wp = w + (size_t)o * C;              // wave-uniform -> s_load
  float acc = 0.f;
  for (int c = 0; c < C; c++) acc += ip[(size_t)c * HW] * wp[c];
  out[idx] = acc;
}

// ---------------- halo attention: one block per (b, 8x8 query tile) ----------------
template <int D>
__global__ __launch_bounds__(256) void attn_kernel(
    const float* __restrict__ qkv, const float* __restrict__ rh, const float* __restrict__ rw,
    float* __restrict__ out, int nh, int nw, int H, int W, long long obStride, int og0, int addFlag) {
  constexpr int DC = (D < 32) ? D : 32;
  constexpr int NCH = D / DC;
  constexpr int HALF = D / 2;
  constexpr int SKS = DC + 4;                       // 16B-aligned row stride
  __shared__ __align__(16) float sQ[64 * SKS];
  __shared__ __align__(16) float sK[100 * SKS];
  __shared__ float sS[64 * 101];
  int blk = blockIdx.x; int nb = nh * nw;
  int b = blk / nb; int r = blk % nb; int by = r / nw; int bx = r % nw;
  size_t HWs = (size_t)H * W;
  const float* qb = qkv + (size_t)b * 3 * D * HWs;
  float qs = rsqrtf((float)D);
  int tid = threadIdx.x;
  for (int i = tid; i < 64 * 101; i += TPB) sS[i] = 0.f;
  // ---- sim = Q K^T, accumulated over d-chunks ----
  for (int ch = 0; ch < NCH; ch++) {
    int dc0 = ch * DC;
    if (ch) __syncthreads();
    for (int idx = tid; idx < 64 * DC; idx += TPB) {
      int i = idx & 63, c = idx >> 6;
      sQ[i * SKS + c] = qb[(size_t)(dc0 + c) * HWs + (size_t)(by * 8 + (i >> 3)) * W + (bx * 8 + (i & 7))] * qs;
    }
    for (int idx = tid; idx < 100 * DC; idx += TPB) {
      int j = idx % 100, c = idx / 100;
      int pr = j / 10, pc = j % 10;
      int hy = by * 8 - 1 + pr, hx = bx * 8 - 1 + pc;
      float v = 0.f;
      if (hy >= 0 && hy < H && hx >= 0 && hx < W)
        v = qb[(size_t)(D + dc0 + c) * HWs + (size_t)hy * W + hx];
      int cg = dc0 + c;
      v += (cg < HALF) ? rh[pr * HALF + cg] : rw[pc * HALF + (cg - HALF)];
      sK[j * SKS + c] = v;
    }
    __syncthreads();
    for (int idx = tid; idx < 6400; idx += TPB) {
      int i = idx / 100, j = idx % 100;
      const float4* q4 = (const float4*)&sQ[i * SKS];
      const float4* k4 = (const float4*)&sK[j * SKS];
      float a = 0.f;
      #pragma unroll
      for (int c4 = 0; c4 < DC / 4; c4++) {
        float4 qv = q4[c4], kv = k4[c4];
        a += qv.x * kv.x + qv.y * kv.y + qv.z * kv.z + qv.w * kv.w;
      }
      sS[i * 101 + j] += a;
    }
  }
  __syncthreads();
  // ---- softmax per query row (lanes 0..63) ----
  if (tid < 64) {
    float mx = -3.4e38f;
    for (int j = 0; j < 100; j++) mx = fmaxf(mx, sS[tid * 101 + j]);
    float s = 0.f;
    for (int j = 0; j < 100; j++) { float e = expf(sS[tid * 101 + j] - mx); sS[tid * 101 + j] = e; s += e; }
    float inv = 1.f / s;
    for (int j = 0; j < 100; j++) sS[tid * 101 + j] *= inv;
  }
  // ---- out = P V, chunked over d ----
  for (int ch = 0; ch < NCH; ch++) {
    int dc0 = ch * DC;
    __syncthreads();
    for (int idx = tid; idx < 100 * DC; idx += TPB) {
      int j = idx % 100, c = idx / 100;
      int pr = j / 10, pc = j % 10;
      int hy = by * 8 - 1 + pr, hx = bx * 8 - 1 + pc;
      float v = 0.f;
      if (hy >= 0 && hy < H && hx >= 0 && hx < W)
        v = qb[(size_t)(2 * D + dc0 + c) * HWs + (size_t)hy * W + hx];
      sK[j * SKS + c] = v;
    }
    __syncthreads();
    for (int idx = tid; idx < 16 * DC; idx += TPB) {
      int i = idx & 63, c4 = idx >> 6;
      float ax = 0.f, ay = 0.f, az = 0.f, aw = 0.f;
      for (int j = 0; j < 100; j++) {
        float s = sS[i * 101 + j];
        float4 kv = ((const float4*)&sK[j * SKS])[c4];
        ax += s * kv.x; ay += s * kv.y; az += s * kv.z; aw += s * kv.w;
      }
      int iy = i >> 3, ix = i & 7;
      size_t o = (size_t)b * obStride + (size_t)(og0 + dc0 + c4 * 4) * HWs + (size_t)(by * 8 + iy) * W + (bx * 8 + ix);
      if (addFlag) { out[o] += ax; out[o + HWs] += ay; out[o + 2 * HWs] += az; out[o + 3 * HWs] += aw; }
      else         { out[o] = ax;  out[o + HWs] = ay;  out[o + 2 * HWs] = az;  out[o + 3 * HWs] = aw; }
    }
  }
}

// ---------------- ff conv 3x3 zero-pad 64->64 + bias + residual (in-place Y) ----------------
__global__ __launch_bounds__(256) void ffconv_kernel(const float* __restrict__ Z,
    const float* __restrict__ w, const float* __restrict__ bias, float* __restrict__ Y) {
  __shared__ float sX[324 * 17];
  int blk = blockIdx.x; int b = blk / 144; int tile = blk % 144;
  int ty = (tile / 12) * 16, tx = (tile % 12) * 16;
  int tid = threadIdx.x;
  int px = tid & 15, py = tid >> 4;
  float acc[64];
  #pragma unroll
  for (int oc = 0; oc < 64; oc++) acc[oc] = 0.f;
  for (int ic0 = 0; ic0 < 64; ic0 += 16) {
    __syncthreads();
    for (int idx = tid; idx < 324 * 16; idx += TPB) {
      int cc = idx / 324; int pix = idx % 324;
      int rr = pix / 18, c = pix % 18;
      int hh = ty + rr - 1, ww = tx + c - 1;
      float v = 0.f;
      if (hh >= 0 && hh < 192 && ww >= 0 && ww < 192)
        v = Z[((size_t)(b * 64 + ic0 + cc) * 192 + hh) * 192 + ww];
      sX[pix * 17 + cc] = v;
    }
    __syncthreads();
    for (int ic = 0; ic < 16; ic++) {
      float xv[9];
      #pragma unroll
      for (int kh = 0; kh < 3; kh++)
        #pragma unroll
        for (int kw = 0; kw < 3; kw++)
          xv[kh * 3 + kw] = sX[((py + kh) * 18 + (px + kw)) * 17 + ic];
      const float* wp = w + (size_t)(ic0 + ic) * 9;   // uniform -> s_load
      #pragma unroll
      for (int oc = 0; oc < 64; oc++) {
        float a = acc[oc];
        const float* wr = wp + (size_t)oc * 576;
        #pragma unroll
        for (int k = 0; k < 9; k++) a += xv[k] * wr[k];
        acc[oc] = a;
      }
    }
  }
  size_t base = (size_t)b * 2359296 + (size_t)(ty + py) * 192 + (tx + px);
  #pragma unroll
  for (int oc = 0; oc < 64; oc++) {
    size_t o = base + (size_t)oc * 36864;
    Y[o] = acc[oc] + bias[oc] + Y[o];
  }
}

// ---------------- Y += R ----------------
__global__ void add_kernel(float* __restrict__ Y, const float* __restrict__ R) {
  int idx = blockIdx.x * TPB + threadIdx.x;
  Y[idx] += R[idx];
}

// ---------------- t1: conv1x1(64->256) + pixel_shuffle(2) + gelu -> U1 (B,64,384,384) ----------------
__global__ __launch_bounds__(256) void t1_kernel(const float* __restrict__ Y,
    const float* __restrict__ w, const float* __restrict__ bias, float* __restrict__ U1) {
  int blk = blockIdx.x; int b = blk / 144; int p0 = (blk % 144) * 256;
  int tid = threadIdx.x;
  int p = p0 + tid;
  float yv[64];
  const float* yp = Y + (size_t)b * 2359296 + p;
  #pragma unroll
  for (int c = 0; c < 64; c++) yv[c] = yp[(size_t)c * 36864];
  int h = p / 192, wc = p % 192;
  float* ub = U1 + (size_t)b * 64 * 147456 + (size_t)(2 * h) * 384 + 2 * wc;
  for (int c2 = 0; c2 < 64; c2++) {
    float a0 = bias[c2 * 4 + 0], a1 = bias[c2 * 4 + 1], a2 = bias[c2 * 4 + 2], a3 = bias[c2 * 4 + 3];
    const float* w0 = w + (size_t)(c2 * 4) * 64;     // uniform -> s_load
    const float* w1 = w0 + 64; const float* w2p = w0 + 128; const float* w3p = w0 + 192;
    #pragma unroll
    for (int c = 0; c < 64; c++) {
      float y = yv[c];
      a0 += y * w0[c]; a1 += y * w1[c]; a2 += y * w2p[c]; a3 += y * w3p[c];
    }
    float* up = ub + (size_t)c2 * 147456;
    up[0] = gelu_f(a0); up[1] = gelu_f(a1); up[384] = gelu_f(a2); up[385] = gelu_f(a3);
  }
}

// ---------------- fused tail: t2 conv1x1+ps+gelu -> t3 conv3x3(reflect) -> clip ----------------
__global__ __launch_bounds__(256) void tail_kernel(const float* __restrict__ U1,
    const float* __restrict__ w2, const float* __restrict__ b2,
    const float* __restrict__ w3, float* __restrict__ out) {
  __shared__ __align__(16) float sU1[100 * 68];     // u1 tile 10x10x64, row stride 68
  __shared__ __align__(16) float sW2[32 * 68];      // 32 rows (8 c2 * 4 parity) of t2_w
  __shared__ float sU2[324 * 9];                    // u2 tile 18x18 x 8-ch chunk (stride 9)
  __shared__ float sB2[256];
  int blk = blockIdx.x;
  int b = blk / 2304; int tile = blk % 2304;
  int r0 = (tile / 48) * 16, c0 = (tile % 48) * 16;
  int tid = threadIdx.x;
  int s0 = r0 / 2 - 1, t0 = c0 / 2 - 1;
  const float* ub = U1 + (size_t)b * 64 * 147456;
  for (int idx = tid; idx < 6400; idx += TPB) {
    int c = idx / 100, pix = idx % 100;
    int si = pix / 10, ti = pix % 10;
    int ss = min(max(s0 + si, 0), 383), tt = min(max(t0 + ti, 0), 383);
    sU1[pix * 68 + c] = ub[(size_t)c * 147456 + (size_t)ss * 384 + tt];
  }
  sB2[tid] = b2[tid];
  int px = tid & 15, py = tid >> 4;
  float acc0 = 0.f, acc1 = 0.f, acc2 = 0.f;
  for (int ch = 0; ch < 8; ch++) {                  // 8 chunks of 8 output channels
    __syncthreads();
    for (int idx = tid; idx < 2048; idx += TPB) {
      int lr = idx >> 6, c = idx & 63;
      sW2[lr * 68 + c] = w2[(size_t)(ch * 32 + lr) * 64 + c];
    }
    __syncthreads();
    for (int idx = tid; idx < 2592; idx += TPB) {   // 324 positions x 8 ch
      int cc = idx & 7, pos = idx >> 3;
      int pq = pos / 18, qq0 = pos % 18;
      int pp = r0 - 1 + pq, qq = c0 - 1 + qq0;
      int mp = (pp < 0) ? -pp : (pp > 767 ? 1534 - pp : pp);
      int mq = (qq < 0) ? -qq : (qq > 767 ? 1534 - qq : qq);
      int par = ((mp & 1) << 1) | (mq & 1);
      int lr = cc * 4 + par;
      int sidx = (mp >> 1) - s0, tidx = (mq >> 1) - t0;
      const float4* u4 = (const float4*)&sU1[(sidx * 10 + tidx) * 68];
      const float4* w4 = (const float4*)&sW2[lr * 68];
      float a = sB2[ch * 32 + lr];
      #pragma unroll
      for (int c4 = 0; c4 < 16; c4++) {
        float4 u = u4[c4], wv = w4[c4];
        a += u.x * wv.x + u.y * wv.y + u.z * wv.z + u.w * wv.w;
      }
      sU2[pos * 9 + cc] = gelu_f(a);
    }
    __syncthreads();
    for (int ic = 0; ic < 8; ic++) {
      int wc = ch * 8 + ic;
      #pragma unroll
      for (int kh = 0; kh < 3; kh++) {
        #pragma unroll
        for (int kw = 0; kw < 3; kw++) {
          float xv = sU2[((py + kh) * 18 + (px + kw)) * 9 + ic];
          acc0 += xv * w3[(size_t)(wc) * 9 + kh * 3 + kw];
          acc1 += xv * w3[(size_t)(64 + wc) * 9 + kh * 3 + kw];
          acc2 += xv * w3[(size_t)(128 + wc) * 9 + kh * 3 + kw];
        }
      }
    }
  }
  size_t o = ((size_t)b * 3 * 768 + (r0 + py)) * 768 + (c0 + px);
  out[o] = fminf(fmaxf(acc0, 0.f), 1.f);
  out[o + 589824] = fminf(fmaxf(acc1, 0.f), 1.f);
  out[o + 1179648] = fminf(fmaxf(acc2, 0.f), 1.f);
}

extern "C" void kernel_launch(void* const* d_in, const int* in_sizes, int n_in,
                              void* d_out, int out_size, void* d_ws, size_t ws_size,
                              hipStream_t stream) {
  const float* x      = (const float*)d_in[0];
  const float* head_w = (const float*)d_in[1];
  const float* head_b = (const float*)d_in[2];
  const float* a_qkv[4] = {(const float*)d_in[3], (const float*)d_in[6], (const float*)d_in[9],  (const float*)d_in[12]};
  const float* a_rh[4]  = {(const float*)d_in[4], (const float*)d_in[7], (const float*)d_in[10], (const float*)d_in[13]};
  const float* a_rw[4]  = {(const float*)d_in[5], (const float*)d_in[8], (const float*)d_in[11], (const float*)d_in[14]};
  const float* ff_w = (const float*)d_in[15];
  const float* ff_b = (const float*)d_in[16];
  const float* t1_w = (const float*)d_in[17];
  const float* t1_b = (const float*)d_in[18];
  const float* t2_w = (const float*)d_in[19];
  const float* t2_b = (const float*)d_in[20];
  const float* t3_w = (const float*)d_in[21];
  float* outp = (float*)d_out;
  float* wsf = (float*)d_ws;

  const size_t F = 9437184;                 // 4*64*192*192
  float* R   = wsf;
  float* Y   = wsf + F;
  float* Z   = wsf + 2 * F;
  float* QKV = wsf + 3 * F;                 // 7,077,888 floats
  float* AO  = QKV + 7077888;               // 2,359,296
  float* D1  = AO + 2359296;                // 2,359,296
  float* D2  = D1 + 2359296;                // 2,359,296
  float* U1  = Z;                           // tail reuses CFTM scratch (needs 37,748,736 floats)

  head_conv_kernel<<<36864, TPB, 0, stream>>>(x, head_w, head_b, R, Y);

  for (int bi = 0; bi < 4; bi++) {
    instnorm_kernel<<<256, TPB, 0, stream>>>(Y, Z);
    // branch 1 (d=16, 192x192)
    qkv_kernel<<<27648, TPB, 0, stream>>>(Z, a_qkv[0] + bi * 768, QKV, 16, 36864, 2359296LL, 0);
    attn_kernel<16><<<2304, TPB, 0, stream>>>(QKV, a_rh[0] + bi * 80, a_rw[0] + bi * 80, Z,
                                              24, 24, 192, 192, 2359296LL, 0, 1);
    // branch 2 (d=64, 96x96)
    mix_kernel<<<9216, TPB, 0, stream>>>(Z, 1);
    dwt_kernel<<<2304, TPB, 0, stream>>>(Z, D1, 16, 192, 192, 2359296LL, 16);
    qkv_kernel<<<27648, TPB, 0, stream>>>(D1, a_qkv[1] + bi * 12288, QKV, 64, 9216, 589824LL, 0);
    attn_kernel<64><<<576, TPB, 0, stream>>>(QKV, a_rh[1] + bi * 320, a_rw[1] + bi * 320, AO,
                                             12, 12, 96, 96, 589824LL, 0, 0);
    iwt_kernel<<<2304, TPB, 0, stream>>>(AO, Z, 16, 96, 96, 2359296LL, 16, 1);
    // branch 3 (d=256, 48x48)
    mix_kernel<<<9216, TPB, 0, stream>>>(Z, 2);
    dwt_kernel<<<2304, TPB, 0, stream>>>(Z, D1, 16, 192, 192, 2359296LL, 32);
    dwt_kernel<<<2304, TPB, 0, stream>>>(D1, D2, 64, 96, 96, 589824LL, 0);
    qkv_kernel<<<27648, TPB, 0, stream>>>(D2, a_qkv[2] + bi * 196608, QKV, 256, 2304, 589824LL, 0);
    attn_kernel<256><<<144, TPB, 0, stream>>>(QKV, a_rh[2] + bi * 1280, a_rw[2] + bi * 1280, AO,
                                              6, 6, 48, 48, 589824LL, 0, 0);
    iwt_kernel<<<2304, TPB, 0, stream>>>(AO, D1, 64, 48, 48, 589824LL, 0, 0);
    iwt_kernel<<<2304, TPB, 0, stream>>>(D1, Z, 16, 96, 96, 2359296LL, 32, 1);
    // branch 4 (d=256, 48x48)
    mix_kernel<<<9216, TPB, 0, stream>>>(Z, 3);
    dwt_kernel<<<2304, TPB, 0, stream>>>(Z, D1, 16, 192, 192, 2359296LL, 48);
    dwt_kernel<<<2304, TPB, 0, stream>>>(D1, D2, 64, 96, 96, 589824LL, 0);
    qkv_kernel<<<27648, TPB, 0, stream>>>(D2, a_qkv[3] + bi * 196608, QKV, 256, 2304, 589824LL, 0);
    attn_kernel<256><<<144, TPB, 0, stream>>>(QKV, a_rh[3] + bi * 1280, a_rw[3] + bi * 1280, AO,
                                              6, 6, 48, 48, 589824LL, 0, 0);
    iwt_kernel<<<2304, TPB, 0, stream>>>(AO, D1, 64, 48, 48, 589824LL, 0, 0);
    iwt_kernel<<<2304, TPB, 0, stream>>>(D1, Z, 16, 96, 96, 2359296LL, 48, 1);
    // ff conv + residual
    ffconv_kernel<<<576, TPB, 0, stream>>>(Z, ff_w + bi * 36864, ff_b + bi * 64, Y);
  }

  add_kernel<<<36864, TPB, 0, stream>>>(Y, R);
  t1_kernel<<<576, TPB, 0, stream>>>(Y, t1_w, t1_b, U1);
  tail_kernel<<<9216, TPB, 0, stream>>>(U1, t2_w, t2_b, t3_w, outp);
}

// Round 3
// 9242.161 us; speedup vs baseline: 1.3397x; 1.3397x over previous
//
#include <hip/hip_runtime.h>
#include <math.h>

#define TPB 256

__device__ __forceinline__ float gelu_f(float x) {
  return 0.5f * x * (1.0f + erff(x * 0.70710678118654752f));
}

// ---------------- head conv 3x3, reflect pad, 3->64, writes R and Y ----------------
__global__ void head_conv_kernel(const float* __restrict__ x, const float* __restrict__ w,
                                 const float* __restrict__ bias, float* __restrict__ R,
                                 float* __restrict__ Y) {
  int idx = blockIdx.x * TPB + threadIdx.x;           // 4*64*192*192
  int wc = idx % 192; int t = idx / 192; int h = t % 192; t /= 192; int oc = t % 64; int b = t / 64;
  float acc = bias[oc];
  #pragma unroll
  for (int kh = 0; kh < 3; kh++) {
    int hh = h + kh - 1; hh = (hh < 0) ? -hh : (hh > 191 ? 382 - hh : hh);
    #pragma unroll
    for (int kw = 0; kw < 3; kw++) {
      int ww = wc + kw - 1; ww = (ww < 0) ? -ww : (ww > 191 ? 382 - ww : ww);
      #pragma unroll
      for (int ic = 0; ic < 3; ic++)
        acc += x[((b * 3 + ic) * 192 + hh) * 192 + ww] * w[((oc * 3 + ic) * 3 + kh) * 3 + kw];
    }
  }
  R[idx] = acc; Y[idx] = acc;
}

// ---------------- instance norm: one block per (b,c) ----------------
__global__ void instnorm_kernel(const float* __restrict__ Y, float* __restrict__ Z) {
  int bc = blockIdx.x;
  const float* in = Y + (size_t)bc * 36864;
  float* out = Z + (size_t)bc * 36864;
  double s = 0.0, s2 = 0.0;
  for (int i = threadIdx.x; i < 36864; i += TPB) { float v = in[i]; s += v; s2 += (double)v * v; }
  __shared__ double sh0[TPB]; __shared__ double sh1[TPB];
  sh0[threadIdx.x] = s; sh1[threadIdx.x] = s2; __syncthreads();
  for (int off = 128; off > 0; off >>= 1) {
    if (threadIdx.x < off) { sh0[threadIdx.x] += sh0[threadIdx.x + off]; sh1[threadIdx.x] += sh1[threadIdx.x + off]; }
    __syncthreads();
  }
  __shared__ float mb, rb;
  if (threadIdx.x == 0) {
    double m = sh0[0] / 36864.0;
    double var = sh1[0] / 36864.0 - m * m;
    mb = (float)m; rb = (float)(1.0 / sqrt(var + 1e-5));
  }
  __syncthreads();
  float m = mb, r = rb;
  for (int i = threadIdx.x; i < 36864; i += TPB) out[i] = (in[i] - m) * r;
}

// ---------------- fused mix + 1-level DWT: Z[g]=(Z[g]+Z[g-1])/2; D = dwt(Z[g]) ----------------
__global__ void mixdwt1_kernel(float* __restrict__ Z, float* __restrict__ D, int g) {
  int idx = blockIdx.x * TPB + threadIdx.x;           // 4*16*96*96 = 589824
  int w2 = idx % 96; int t = idx / 96; int h2 = t % 96; t /= 96; int c = t % 16; int b = t / 16;
  float* zb = Z + (size_t)b * 2359296 + (size_t)(g * 16 + c) * 36864;
  const float* pb = zb - 589824;
  int r0 = (2 * h2) * 192 + 2 * w2;
  float2 top = *(float2*)&zb[r0]; float2 bot = *(float2*)&zb[r0 + 192];
  float2 pt = *(const float2*)&pb[r0]; float2 pbm = *(const float2*)&pb[r0 + 192];
  float a  = 0.5f * (top.x + pt.x);   // even row, even col
  float cc = 0.5f * (top.y + pt.y);   // even row, odd col
  float bb = 0.5f * (bot.x + pbm.x);  // odd row, even col
  float dd = 0.5f * (bot.y + pbm.y);  // odd row, odd col
  *(float2*)&zb[r0] = make_float2(a, cc);
  *(float2*)&zb[r0 + 192] = make_float2(bb, dd);
  size_t ob = ((size_t)b * 64 + c) * 9216 + (size_t)h2 * 96 + w2;
  D[ob]             = 0.5f * ( a + bb + cc + dd);
  D[ob + 16 * 9216] = 0.5f * (-a - bb + cc + dd);
  D[ob + 32 * 9216] = 0.5f * (-a + bb - cc + dd);
  D[ob + 48 * 9216] = 0.5f * ( a - bb - cc + dd);
}

// ---------------- fused mix + 2-level DWT: Z[g]=(Z[g]+Z[g-1])/2; D = dwt(dwt(Z[g])) ----------------
__global__ void mixdwt2_kernel(float* __restrict__ Z, float* __restrict__ D, int g) {
  int idx = blockIdx.x * TPB + threadIdx.x;           // 4*16*48*48 = 147456
  int w4 = idx % 48; int t = idx / 48; int h4 = t % 48; t /= 48; int c = t % 16; int b = t / 16;
  float* zb = Z + (size_t)b * 2359296 + (size_t)(g * 16 + c) * 36864;
  const float* pb = zb - 589824;
  float m[4][4];
  #pragma unroll
  for (int r = 0; r < 4; r++) {
    int off = (4 * h4 + r) * 192 + 4 * w4;
    float4 v = *(float4*)&zb[off];
    float4 pv = *(const float4*)&pb[off];
    m[r][0] = 0.5f * (v.x + pv.x); m[r][1] = 0.5f * (v.y + pv.y);
    m[r][2] = 0.5f * (v.z + pv.z); m[r][3] = 0.5f * (v.w + pv.w);
    *(float4*)&zb[off] = make_float4(m[r][0], m[r][1], m[r][2], m[r][3]);
  }
  float A[4][2][2];                                    // [s1][p][q]
  #pragma unroll
  for (int p = 0; p < 2; p++)
    #pragma unroll
    for (int q = 0; q < 2; q++) {
      float a  = m[2 * p][2 * q];
      float bb = m[2 * p + 1][2 * q];
      float cc = m[2 * p][2 * q + 1];
      float dd = m[2 * p + 1][2 * q + 1];
      A[0][p][q] = 0.5f * ( a + bb + cc + dd);
      A[1][p][q] = 0.5f * (-a - bb + cc + dd);
      A[2][p][q] = 0.5f * (-a + bb - cc + dd);
      A[3][p][q] = 0.5f * ( a - bb - cc + dd);
    }
  // FIX (round 2 bug): channel term c*2304 was missing -> all c raced into slot 0.
  size_t ob = (size_t)b * 589824 + (size_t)c * 2304 + (size_t)h4 * 48 + w4;
  #pragma unroll
  for (int s1 = 0; s1 < 4; s1++) {
    float a = A[s1][0][0], bb = A[s1][1][0], cc = A[s1][0][1], dd = A[s1][1][1];
    size_t o = ob + (size_t)(s1 * 16) * 2304;
    D[o]                = 0.5f * ( a + bb + cc + dd);
    D[o +  64 * 2304]   = 0.5f * (-a - bb + cc + dd);
    D[o + 128 * 2304]   = 0.5f * (-a + bb - cc + dd);
    D[o + 192 * 2304]   = 0.5f * ( a - bb - cc + dd);
  }
}

// ---------------- IWT (1-level): (B,4C,H,W) -> add into strided dest ----------------
__global__ void iwt_kernel(const float* __restrict__ in, float* __restrict__ out,
                           int C, int H, int W, long long obStride, int og0, int addFlag) {
  int idx = blockIdx.x * TPB + threadIdx.x;
  int w = idx % W; int t = idx / W; int h = t % H; t /= H; int c = t % C; int b = t / C;
  size_t HW = (size_t)H * W; size_t CHW = (size_t)C * HW;
  size_t base = (size_t)b * 4 * CHW + (size_t)c * HW + (size_t)h * W + w;
  float x1 = in[base], x2 = in[base + CHW], x3 = in[base + 2 * CHW], x4 = in[base + 3 * CHW];
  float p00 = 0.5f * (x1 - x2 - x3 + x4);
  float p10 = 0.5f * (x1 - x2 + x3 - x4);
  float p01 = 0.5f * (x1 + x2 - x3 - x4);
  float p11 = 0.5f * (x1 + x2 + x3 + x4);
  int W2 = 2 * W;
  float* op = out + (size_t)b * obStride + (size_t)(og0 + c) * (4 * HW) + (size_t)(2 * h) * W2 + 2 * w;
  if (addFlag) { op[0] += p00; op[1] += p01; op[W2] += p10; op[W2 + 1] += p11; }
  else         { op[0] = p00;  op[1] = p01;  op[W2] = p10;  op[W2 + 1] = p11; }
}

// ---------------- fused 2-level IWT + residual add into Z[g] ----------------
__global__ void iwt2add_kernel(const float* __restrict__ X, float* __restrict__ Z, int g) {
  int idx = blockIdx.x * TPB + threadIdx.x;           // 4*16*48*48 = 147456
  int w = idx % 48; int t = idx / 48; int h = t % 48; t /= 48; int c = t % 16; int b = t / 16;
  const float* xb = X + (size_t)b * 589824 + (size_t)h * 48 + w;
  float xv[4][4];                                      // [s2][s1]
  #pragma unroll
  for (int s2 = 0; s2 < 4; s2++)
    #pragma unroll
    for (int s1 = 0; s1 < 4; s1++)
      xv[s2][s1] = xb[(size_t)(s2 * 64 + s1 * 16 + c) * 2304];
  float Yv[4][2][2];                                   // [s1][p][q]
  #pragma unroll
  for (int s1 = 0; s1 < 4; s1++) {
    float X0 = xv[0][s1], X1 = xv[1][s1], X2 = xv[2][s1], X3 = xv[3][s1];
    Yv[s1][0][0] = 0.5f * (X0 - X1 - X2 + X3);
    Yv[s1][0][1] = 0.5f * (X0 + X1 - X2 - X3);
    Yv[s1][1][0] = 0.5f * (X0 - X1 + X2 - X3);
    Yv[s1][1][1] = 0.5f * (X0 + X1 + X2 + X3);
  }
  float* zb = Z + (size_t)b * 2359296 + (size_t)(g * 16 + c) * 36864;
  #pragma unroll
  for (int p = 0; p < 2; p++)
    #pragma unroll
    for (int i = 0; i < 2; i++) {
      float Y0q0 = Yv[0][p][0], Y1q0 = Yv[1][p][0], Y2q0 = Yv[2][p][0], Y3q0 = Yv[3][p][0];
      float Y0q1 = Yv[0][p][1], Y1q1 = Yv[1][p][1], Y2q1 = Yv[2][p][1], Y3q1 = Yv[3][p][1];
      float si = (i == 0) ? -1.f : 1.f;
      float zq0j0 = 0.5f * (Y0q0 - Y1q0 + si * Y2q0 - si * Y3q0);
      float zq0j1 = 0.5f * (Y0q0 + Y1q0 + si * Y2q0 + si * Y3q0);
      float zq1j0 = 0.5f * (Y0q1 - Y1q1 + si * Y2q1 - si * Y3q1);
      float zq1j1 = 0.5f * (Y0q1 + Y1q1 + si * Y2q1 + si * Y3q1);
      int off = (4 * h + 2 * p + i) * 192 + 4 * w;
      float4 cur = *(float4*)&zb[off];
      cur.x += zq0j0; cur.y += zq0j1; cur.z += zq1j0; cur.w += zq1j1;
      *(float4*)&zb[off] = cur;
    }
}

// ---------------- qkv einsum, register-tiled: 16 outputs per thread ----------------
__global__ __launch_bounds__(256) void qkv_kernel(const float* __restrict__ in, const float* __restrict__ w,
                           float* __restrict__ out, int C, int HW, long long ibStride, int ig0) {
  int PT = HW >> 8;
  int OT3 = (3 * C) >> 4;
  int blk = blockIdx.x;
  int pt = blk % PT; int t = blk / PT; int ot = t % OT3; int b = t / OT3;
  int p = pt * 256 + threadIdx.x;
  const float* ip = in + (size_t)b * ibStride + (size_t)ig0 * HW + p;
  int o0 = ot * 16;
  float acc[16];
  #pragma unroll
  for (int i = 0; i < 16; i++) acc[i] = 0.f;
  for (int c = 0; c < C; c += 4) {
    float v0 = ip[(size_t)c * HW], v1 = ip[(size_t)(c + 1) * HW];
    float v2 = ip[(size_t)(c + 2) * HW], v3 = ip[(size_t)(c + 3) * HW];
    #pragma unroll
    for (int i = 0; i < 16; i++) {
      const float4 wv = *(const float4*)(w + (size_t)(o0 + i) * C + c);   // uniform -> s_load_dwordx4
      acc[i] += v0 * wv.x + v1 * wv.y + v2 * wv.z + v3 * wv.w;
    }
  }
  float* op = out + ((size_t)b * 3 * C + o0) * HW + p;
  #pragma unroll
  for (int i = 0; i < 16; i++) op[(size_t)i * HW] = acc[i];
}

// ---------------- halo attention: one block per (b, 8x8 query tile) ----------------
template <int D>
__global__ __launch_bounds__(256) void attn_kernel(
    const float* __restrict__ qkv, const float* __restrict__ rh, const float* __restrict__ rw,
    float* __restrict__ out, int nh, int nw, int H, int W, long long obStride, int og0, int addFlag) {
  constexpr int DC = (D < 32) ? D : 32;
  constexpr int NCH = D / DC;
  constexpr int HALF = D / 2;
  constexpr int SKS = DC + 4;
  __shared__ __align__(16) float sQ[64 * SKS];
  __shared__ __align__(16) float sK[100 * SKS];
  __shared__ float sS[64 * 101];
  int blk = blockIdx.x; int nb = nh * nw;
  int b = blk / nb; int r = blk % nb; int by = r / nw; int bx = r % nw;
  size_t HWs = (size_t)H * W;
  const float* qb = qkv + (size_t)b * 3 * D * HWs;
  float qs = rsqrtf((float)D);
  int tid = threadIdx.x;
  for (int i = tid; i < 64 * 101; i += TPB) sS[i] = 0.f;
  for (int ch = 0; ch < NCH; ch++) {
    int dc0 = ch * DC;
    if (ch) __syncthreads();
    for (int idx = tid; idx < 64 * DC; idx += TPB) {
      int i = idx & 63, c = idx >> 6;
      sQ[i * SKS + c] = qb[(size_t)(dc0 + c) * HWs + (size_t)(by * 8 + (i >> 3)) * W + (bx * 8 + (i & 7))] * qs;
    }
    for (int idx = tid; idx < 100 * DC; idx += TPB) {
      int j = idx % 100, c = idx / 100;
      int pr = j / 10, pc = j % 10;
      int hy = by * 8 - 1 + pr, hx = bx * 8 - 1 + pc;
      float v = 0.f;
      if (hy >= 0 && hy < H && hx >= 0 && hx < W)
        v = qb[(size_t)(D + dc0 + c) * HWs + (size_t)hy * W + hx];
      int cg = dc0 + c;
      v += (cg < HALF) ? rh[pr * HALF + cg] : rw[pc * HALF + (cg - HALF)];
      sK[j * SKS + c] = v;
    }
    __syncthreads();
    for (int idx = tid; idx < 6400; idx += TPB) {
      int i = idx / 100, j = idx % 100;
      const float4* q4 = (const float4*)&sQ[i * SKS];
      const float4* k4 = (const float4*)&sK[j * SKS];
      float a = 0.f;
      #pragma unroll
      for (int c4 = 0; c4 < DC / 4; c4++) {
        float4 qv = q4[c4], kv = k4[c4];
        a += qv.x * kv.x + qv.y * kv.y + qv.z * kv.z + qv.w * kv.w;
      }
      sS[i * 101 + j] += a;
    }
  }
  __syncthreads();
  if (tid < 64) {
    float mx = -3.4e38f;
    for (int j = 0; j < 100; j++) mx = fmaxf(mx, sS[tid * 101 + j]);
    float s = 0.f;
    for (int j = 0; j < 100; j++) { float e = expf(sS[tid * 101 + j] - mx); sS[tid * 101 + j] = e; s += e; }
    float inv = 1.f / s;
    for (int j = 0; j < 100; j++) sS[tid * 101 + j] *= inv;
  }
  for (int ch = 0; ch < NCH; ch++) {
    int dc0 = ch * DC;
    __syncthreads();
    for (int idx = tid; idx < 100 * DC; idx += TPB) {
      int j = idx % 100, c = idx / 100;
      int pr = j / 10, pc = j % 10;
      int hy = by * 8 - 1 + pr, hx = bx * 8 - 1 + pc;
      float v = 0.f;
      if (hy >= 0 && hy < H && hx >= 0 && hx < W)
        v = qb[(size_t)(2 * D + dc0 + c) * HWs + (size_t)hy * W + hx];
      sK[j * SKS + c] = v;
    }
    __syncthreads();
    for (int idx = tid; idx < 16 * DC; idx += TPB) {
      int i = idx & 63, c4 = idx >> 6;
      float ax = 0.f, ay = 0.f, az = 0.f, aw = 0.f;
      for (int j = 0; j < 100; j++) {
        float s = sS[i * 101 + j];
        float4 kv = ((const float4*)&sK[j * SKS])[c4];
        ax += s * kv.x; ay += s * kv.y; az += s * kv.z; aw += s * kv.w;
      }
      int iy = i >> 3, ix = i & 7;
      size_t o = (size_t)b * obStride + (size_t)(og0 + dc0 + c4 * 4) * HWs + (size_t)(by * 8 + iy) * W + (bx * 8 + ix);
      if (addFlag) { out[o] += ax; out[o + HWs] += ay; out[o + 2 * HWs] += az; out[o + 3 * HWs] += aw; }
      else         { out[o] = ax;  out[o + HWs] = ay;  out[o + 2 * HWs] = az;  out[o + 3 * HWs] = aw; }
    }
  }
}

// ---------------- ff conv 3x3 zero-pad 64->64 + bias + residual (in-place Y) ----------------
__global__ __launch_bounds__(256) void ffconv_kernel(const float* __restrict__ Z,
    const float* __restrict__ w, const float* __restrict__ bias, float* __restrict__ Y) {
  __shared__ float sX[324 * 17];
  int blk = blockIdx.x; int b = blk / 144; int tile = blk % 144;
  int ty = (tile / 12) * 16, tx = (tile % 12) * 16;
  int tid = threadIdx.x;
  int px = tid & 15, py = tid >> 4;
  float acc[64];
  #pragma unroll
  for (int oc = 0; oc < 64; oc++) acc[oc] = 0.f;
  for (int ic0 = 0; ic0 < 64; ic0 += 16) {
    __syncthreads();
    for (int idx = tid; idx < 324 * 16; idx += TPB) {
      int cc = idx / 324; int pix = idx % 324;
      int rr = pix / 18, c = pix % 18;
      int hh = ty + rr - 1, ww = tx + c - 1;
      float v = 0.f;
      if (hh >= 0 && hh < 192 && ww >= 0 && ww < 192)
        v = Z[((size_t)(b * 64 + ic0 + cc) * 192 + hh) * 192 + ww];
      sX[pix * 17 + cc] = v;
    }
    __syncthreads();
    for (int ic = 0; ic < 16; ic++) {
      float xv[9];
      #pragma unroll
      for (int kh = 0; kh < 3; kh++)
        #pragma unroll
        for (int kw = 0; kw < 3; kw++)
          xv[kh * 3 + kw] = sX[((py + kh) * 18 + (px + kw)) * 17 + ic];
      const float* wp = w + (size_t)(ic0 + ic) * 9;
      #pragma unroll
      for (int oc = 0; oc < 64; oc++) {
        float a = acc[oc];
        const float* wr = wp + (size_t)oc * 576;
        #pragma unroll
        for (int k = 0; k < 9; k++) a += xv[k] * wr[k];
        acc[oc] = a;
      }
    }
  }
  size_t base = (size_t)b * 2359296 + (size_t)(ty + py) * 192 + (tx + px);
  #pragma unroll
  for (int oc = 0; oc < 64; oc++) {
    size_t o = base + (size_t)oc * 36864;
    Y[o] = acc[oc] + bias[oc] + Y[o];
  }
}

// ---------------- t1: (Y+R) conv1x1(64->256) + pixel_shuffle(2) + gelu -> U1 ----------------
__global__ __launch_bounds__(256) void t1_kernel(const float* __restrict__ Y, const float* __restrict__ R,
    const float* __restrict__ w, const float* __restrict__ bias, float* __restrict__ U1) {
  int blk = blockIdx.x; int b = blk / 144; int p0 = (blk % 144) * 256;
  int tid = threadIdx.x;
  int p = p0 + tid;
  float yv[64];
  const float* yp = Y + (size_t)b * 2359296 + p;
  const float* rp = R + (size_t)b * 2359296 + p;
  #pragma unroll
  for (int c = 0; c < 64; c++) yv[c] = yp[(size_t)c * 36864] + rp[(size_t)c * 36864];
  int h = p / 192, wc = p % 192;
  float* ub = U1 + (size_t)b * 9437184 + (size_t)(2 * h) * 384 + 2 * wc;
  for (int c2 = 0; c2 < 64; c2++) {
    float a0 = bias[c2 * 4 + 0], a1 = bias[c2 * 4 + 1], a2 = bias[c2 * 4 + 2], a3 = bias[c2 * 4 + 3];
    const float* w0 = w + (size_t)(c2 * 4) * 64;
    const float* w1 = w0 + 64; const float* w2p = w0 + 128; const float* w3p = w0 + 192;
    #pragma unroll
    for (int c = 0; c < 64; c++) {
      float y = yv[c];
      a0 += y * w0[c]; a1 += y * w1[c]; a2 += y * w2p[c]; a3 += y * w3p[c];
    }
    float* up = ub + (size_t)c2 * 147456;
    up[0] = gelu_f(a0); up[1] = gelu_f(a1); up[384] = gelu_f(a2); up[385] = gelu_f(a3);
  }
}

// ---------------- fused tail: t2 conv1x1+ps+gelu -> t3 conv3x3(reflect) -> clip ----------------
// 28x28 output tile; u1 16x16 held per-thread in VGPRs; t2 weights via s_load; only u2 in LDS.
__global__ __launch_bounds__(256) void tail_kernel(const float* __restrict__ U1,
    const float* __restrict__ w2, const float* __restrict__ b2,
    const float* __restrict__ w3, float* __restrict__ out) {
  __shared__ float sU2[32 * 32 * 10];                 // [u2 pix (32x32)][8 ic], stride 10
  int blk = blockIdx.x;
  int b = blk / 784; int tile = blk % 784;
  int tr = tile / 28, tc = tile % 28;
  int r0 = tr * 28, c0 = tc * 28;
  int s0 = (r0 >> 1) - 1, t0 = (c0 >> 1) - 1;
  int tid = threadIdx.x;
  int ls = tid >> 4, lt = tid & 15;
  int gs = min(max(s0 + ls, 0), 383);
  int gt = min(max(t0 + lt, 0), 383);
  const float* ub = U1 + (size_t)b * 9437184 + (size_t)gs * 384 + gt;
  float u1v[64];
  #pragma unroll
  for (int c = 0; c < 64; c++) u1v[c] = ub[(size_t)c * 147456];
  float acc[4][3];
  #pragma unroll
  for (int k = 0; k < 4; k++) { acc[k][0] = 0.f; acc[k][1] = 0.f; acc[k][2] = 0.f; }
  int urow = 2 * ls, ucol = 2 * lt;
  for (int ch = 0; ch < 8; ch++) {
    if (ch) __syncthreads();
    float a[4][8];                                    // [par][g]
    #pragma unroll
    for (int g = 0; g < 8; g++) {
      #pragma unroll
      for (int par = 0; par < 4; par++) {
        int row = (ch * 8 + g) * 4 + par;
        const float* wp = w2 + (size_t)row * 64;      // uniform -> s_load
        float s = b2[row];
        #pragma unroll
        for (int c = 0; c < 64; c++) s += u1v[c] * wp[c];
        a[par][g] = gelu_f(s);
      }
    }
    #pragma unroll
    for (int par = 0; par < 4; par++) {
      int pix = (urow + (par >> 1)) * 32 + (ucol + (par & 1));
      float2* dst = (float2*)&sU2[pix * 10];
      dst[0] = make_float2(a[par][0], a[par][1]);
      dst[1] = make_float2(a[par][2], a[par][3]);
      dst[2] = make_float2(a[par][4], a[par][5]);
      dst[3] = make_float2(a[par][6], a[par][7]);
    }
    __syncthreads();
    #pragma unroll
    for (int k = 0; k < 4; k++) {
      int p = tid + k * 256;
      if (p >= 784) continue;
      int oy = p / 28, ox = p % 28;
      int r = r0 + oy, c = c0 + ox;
      if (r >= 768 || c >= 768) continue;
      float s0a = acc[k][0], s1a = acc[k][1], s2a = acc[k][2];
      #pragma unroll
      for (int kh = 0; kh < 3; kh++) {
        int pp = r - 1 + kh; int mp = pp < 0 ? -pp : (pp > 767 ? 1534 - pp : pp);
        int lr = mp - r0 + 2;
        #pragma unroll
        for (int kw = 0; kw < 3; kw++) {
          int qq = c - 1 + kw; int mq = qq < 0 ? -qq : (qq > 767 ? 1534 - qq : qq);
          int lc = mq - c0 + 2;
          const float2* u = (const float2*)&sU2[(lr * 32 + lc) * 10];
          float2 u01 = u[0], u23 = u[1], u45 = u[2], u67 = u[3];
          const float* w3p = w3 + (size_t)(ch * 8) * 9 + kh * 3 + kw;   // + oc*576 + g*9
          s0a += u01.x * w3p[0]    + u01.y * w3p[9]    + u23.x * w3p[18]   + u23.y * w3p[27]
               + u45.x * w3p[36]   + u45.y * w3p[45]   + u67.x * w3p[54]   + u67.y * w3p[63];
          s1a += u01.x * w3p[576]  + u01.y * w3p[585]  + u23.x * w3p[594]  + u23.y * w3p[603]
               + u45.x * w3p[612]  + u45.y * w3p[621]  + u67.x * w3p[630]  + u67.y * w3p[639];
          s2a += u01.x * w3p[1152] + u01.y * w3p[1161] + u23.x * w3p[1170] + u23.y * w3p[1179]
               + u45.x * w3p[1188] + u45.y * w3p[1197] + u67.x * w3p[1206] + u67.y * w3p[1215];
        }
      }
      acc[k][0] = s0a; acc[k][1] = s1a; acc[k][2] = s2a;
    }
  }
  #pragma unroll
  for (int k = 0; k < 4; k++) {
    int p = tid + k * 256;
    if (p >= 784) continue;
    int oy = p / 28, ox = p % 28;
    int r = r0 + oy, c = c0 + ox;
    if (r >= 768 || c >= 768) continue;
    size_t o = ((size_t)b * 3 * 768 + r) * 768 + c;
    out[o] = fminf(fmaxf(acc[k][0], 0.f), 1.f);
    out[o + 589824] = fminf(fmaxf(acc[k][1], 0.f), 1.f);
    out[o + 1179648] = fminf(fmaxf(acc[k][2], 0.f), 1.f);
  }
}

extern "C" void kernel_launch(void* const* d_in, const int* in_sizes, int n_in,
                              void* d_out, int out_size, void* d_ws, size_t ws_size,
                              hipStream_t stream) {
  const float* x      = (const float*)d_in[0];
  const float* head_w = (const float*)d_in[1];
  const float* head_b = (const float*)d_in[2];
  const float* a_qkv[4] = {(const float*)d_in[3], (const float*)d_in[6], (const float*)d_in[9],  (const float*)d_in[12]};
  const float* a_rh[4]  = {(const float*)d_in[4], (const float*)d_in[7], (const float*)d_in[10], (const float*)d_in[13]};
  const float* a_rw[4]  = {(const float*)d_in[5], (const float*)d_in[8], (const float*)d_in[11], (const float*)d_in[14]};
  const float* ff_w = (const float*)d_in[15];
  const float* ff_b = (const float*)d_in[16];
  const float* t1_w = (const float*)d_in[17];
  const float* t1_b = (const float*)d_in[18];
  const float* t2_w = (const float*)d_in[19];
  const float* t2_b = (const float*)d_in[20];
  const float* t3_w = (const float*)d_in[21];
  float* outp = (float*)d_out;
  float* wsf = (float*)d_ws;

  const size_t F = 9437184;                 // 4*64*192*192
  float* R   = wsf;
  float* Y   = wsf + F;
  float* Z   = wsf + 2 * F;
  float* QKV = wsf + 3 * F;                 // 7,077,888 floats
  float* AO  = QKV + 7077888;               // 2,359,296
  float* D1  = AO + 2359296;                // 2,359,296
  float* D2  = D1 + 2359296;                // 2,359,296
  float* U1  = Z;                           // tail reuses CFTM scratch

  head_conv_kernel<<<36864, TPB, 0, stream>>>(x, head_w, head_b, R, Y);

  for (int bi = 0; bi < 4; bi++) {
    instnorm_kernel<<<256, TPB, 0, stream>>>(Y, Z);
    // branch 1 (d=16, 192x192)
    qkv_kernel<<<1728, TPB, 0, stream>>>(Z, a_qkv[0] + bi * 768, QKV, 16, 36864, 2359296LL, 0);
    attn_kernel<16><<<2304, TPB, 0, stream>>>(QKV, a_rh[0] + bi * 80, a_rw[0] + bi * 80, Z,
                                              24, 24, 192, 192, 2359296LL, 0, 1);
    // branch 2 (d=64, 96x96)
    mixdwt1_kernel<<<2304, TPB, 0, stream>>>(Z, D1, 1);
    qkv_kernel<<<1728, TPB, 0, stream>>>(D1, a_qkv[1] + bi * 12288, QKV, 64, 9216, 589824LL, 0);
    attn_kernel<64><<<576, TPB, 0, stream>>>(QKV, a_rh[1] + bi * 320, a_rw[1] + bi * 320, AO,
                                             12, 12, 96, 96, 589824LL, 0, 0);
    iwt_kernel<<<2304, TPB, 0, stream>>>(AO, Z, 16, 96, 96, 2359296LL, 16, 1);
    // branch 3 (d=256, 48x48)
    mixdwt2_kernel<<<576, TPB, 0, stream>>>(Z, D2, 2);
    qkv_kernel<<<1728, TPB, 0, stream>>>(D2, a_qkv[2] + bi * 196608, QKV, 256, 2304, 589824LL, 0);
    attn_kernel<256><<<144, TPB, 0, stream>>>(QKV, a_rh[2] + bi * 1280, a_rw[2] + bi * 1280, AO,
                                              6, 6, 48, 48, 589824LL, 0, 0);
    iwt2add_kernel<<<576, TPB, 0, stream>>>(AO, Z, 2);
    // branch 4 (d=256, 48x48)
    mixdwt2_kernel<<<576, TPB, 0, stream>>>(Z, D2, 3);
    qkv_kernel<<<1728, TPB, 0, stream>>>(D2, a_qkv[3] + bi * 196608, QKV, 256, 2304, 589824LL, 0);
    attn_kernel<256><<<144, TPB, 0, stream>>>(QKV, a_rh[3] + bi * 1280, a_rw[3] + bi * 1280, AO,
                                              6, 6, 48, 48, 589824LL, 0, 0);
    iwt2add_kernel<<<576, TPB, 0, stream>>>(AO, Z, 3);
    // ff conv + residual
    ffconv_kernel<<<576, TPB, 0, stream>>>(Z, ff_w + bi * 36864, ff_b + bi * 64, Y);
  }

  t1_kernel<<<576, TPB, 0, stream>>>(Y, R, t1_w, t1_b, U1);
  tail_kernel<<<3136, TPB, 0, stream>>>(U1, t2_w, t2_b, t3_w, outp);
}